// Round 5
// baseline (148.649 us; speedup 1.0000x reference)
//
#include <hip/hip_runtime.h>
#include <math.h>

#define NCAPS 8
#define SEQ 200
#define EMB 128
#define CDIM 64
#define NROUNDS 3
#define NT 512
#define BPAD 68    // sBeh row pad: 272B rows, 16B-aligned, banks shift by 4/row
#define CPAD 68

typedef __bf16 bf16x8 __attribute__((ext_vector_type(8)));
typedef float f32x4 __attribute__((ext_vector_type(4)));
typedef unsigned short ushort8 __attribute__((ext_vector_type(8)));

__device__ __forceinline__ float4 ld4(const float* p) { return *reinterpret_cast<const float4*>(p); }
__device__ __forceinline__ void st4(float* p, float4 v) { *reinterpret_cast<float4*>(p) = v; }

// RNE float -> bf16 bits
__device__ __forceinline__ unsigned short f2bf(float v) {
  unsigned u = __builtin_bit_cast(unsigned, v);
  u += 0x7FFFu + ((u >> 16) & 1u);
  return (unsigned short)(u >> 16);
}
__device__ __forceinline__ float bf2f(unsigned short b) {
  unsigned u = ((unsigned)b) << 16;
  return __builtin_bit_cast(float, u);
}

// One-time: split S (128x64 fp32) into MFMA-fragment-ordered bf16 hi/lo.
// Element (e,d) -> frag fi = (e>>5)*4 + (d>>4), lane = ((e>>3)&3)*16 + (d&15), j = e&7.
// ws layout: ushort hi[16*64*8] then lo[16*64*8]  (32 KB total)
__global__ void split_S_kernel(const float* __restrict__ S, unsigned short* __restrict__ wsS) {
  int i = blockIdx.x * 256 + threadIdx.x;
  if (i >= EMB * CDIM) return;
  int e = i >> 6, d = i & 63;
  float v = S[i];
  unsigned short h = f2bf(v);
  unsigned short lo = f2bf(v - bf2f(h));
  int fi = (e >> 5) * 4 + (d >> 4);
  int ln = (((e >> 3) & 3) << 4) + (d & 15);
  int j = e & 7;
  wsS[(fi * 64 + ln) * 8 + j] = h;
  wsS[EMB * CDIM + (fi * 64 + ln) * 8 + j] = lo;
}

template <bool USE_WS>
__global__ __launch_bounds__(NT, USE_WS ? 4 : 2) void mie_kernel(
    const float* __restrict__ behaviors,       // [B][200][128]
    const unsigned char* __restrict__ maskraw, // bool bytes OR int32 OR float32 (detected)
    const float* __restrict__ S,               // [128][64] (only used if !USE_WS)
    const float* __restrict__ B0,              // [8][200]
    const unsigned short* __restrict__ SfG,    // fragment-ordered S hi/lo (if USE_WS)
    float* __restrict__ out)                   // [B][8][64]
{
  __shared__ float sBeh[SEQ][BPAD];     // 54.4 KB (fp32 projection output)
  __shared__ float sB[NCAPS][SEQ];      // 6.4 KB
  __shared__ float sW[NCAPS][SEQ];      // 6.4 KB
  __shared__ float sCaps[NCAPS][CPAD];  // 2.2 KB
  __shared__ float sMask[SEQ];          // 0.8 KB
  __shared__ int sFlagA, sFlagB;
  __shared__ ushort8 sSfH[USE_WS ? 1 : 16 * 64];  // fallback-only S staging
  __shared__ ushort8 sSfL[USE_WS ? 1 : 16 * 64];
  // USE_WS total ~70.3 KB -> 2 blocks/CU (16 waves/CU)

  const int b = blockIdx.x;
  const int t = threadIdx.x;
  const int lane = t & 63;
  const int w = t >> 6;

  // ---- detect mask dtype over first 1KB ----
  if (t == 0) { sFlagA = 0; sFlagB = 0; }
  __syncthreads();
  for (int i = t; i < 1024; i += NT) {
    unsigned char v = maskraw[i];
    if (v != 0) {
      int m = i & 3;
      if (m == 1) atomicOr(&sFlagA, 1);
      else if (m >= 2) atomicOr(&sFlagB, 1);
    }
  }
  __syncthreads();
  const int mode = sFlagA ? 1 : (sFlagB ? 2 : 0);  // 1=bytes, 2=float32, 0=int32

  // ---- load mask, B0 (and fallback S staging) ----
  if (mode == 1) {
    for (int i = t; i < SEQ; i += NT)
      sMask[i] = maskraw[(size_t)b * SEQ + i] ? 1.0f : 0.0f;
  } else if (mode == 2) {
    const float* mf = (const float*)maskraw;
    for (int i = t; i < SEQ; i += NT)
      sMask[i] = (mf[(size_t)b * SEQ + i] != 0.0f) ? 1.0f : 0.0f;
  } else {
    const int* mi = (const int*)maskraw;
    for (int i = t; i < SEQ; i += NT)
      sMask[i] = mi[(size_t)b * SEQ + i] ? 1.0f : 0.0f;
  }
  for (int i = t; i < NCAPS * SEQ; i += NT)
    (&sB[0][0])[i] = B0[i];

  if constexpr (!USE_WS) {
    for (int i = t; i < EMB * CDIM; i += NT) {
      int e = i >> 6, d = i & 63;
      float v = S[i];
      unsigned short h = f2bf(v);
      unsigned short lo = f2bf(v - bf2f(h));
      int fi = (e >> 5) * 4 + (d >> 4);
      int ln = (((e >> 3) & 3) << 4) + (d & 15);
      int j = e & 7;
      ((unsigned short*)&sSfH[fi * 64 + ln])[j] = h;
      ((unsigned short*)&sSfL[fi * 64 + ln])[j] = lo;
    }
  }
  __syncthreads();

  // ---- projection via MFMA: sBeh = behaviors[b] @ S  (split-bf16, 3 terms) ----
  {
    const int fr = lane & 15;   // A row-in-tile; also C col-in-tile
    const int kg = lane >> 4;   // k-group (0..3)
    for (int rt = w; rt < 13; rt += 8) {
      const int r0 = rt * 16;
      const int row = r0 + fr;
      bf16x8 aH[4], aL[4];
#pragma unroll
      for (int ks = 0; ks < 4; ++ks) {
        float a[8];
        if (row < SEQ) {
          const float* p = behaviors + ((size_t)b * SEQ + row) * EMB + ks * 32 + kg * 8;
          float4 u0 = ld4(p), u1 = ld4(p + 4);
          a[0] = u0.x; a[1] = u0.y; a[2] = u0.z; a[3] = u0.w;
          a[4] = u1.x; a[5] = u1.y; a[6] = u1.z; a[7] = u1.w;
        } else {
#pragma unroll
          for (int j = 0; j < 8; ++j) a[j] = 0.f;
        }
        ushort8 h, lo;
#pragma unroll
        for (int j = 0; j < 8; ++j) {
          unsigned short hh = f2bf(a[j]);
          h[j] = hh;
          lo[j] = f2bf(a[j] - bf2f(hh));
        }
        aH[ks] = __builtin_bit_cast(bf16x8, h);
        aL[ks] = __builtin_bit_cast(bf16x8, lo);
      }
#pragma unroll
      for (int ct = 0; ct < 4; ++ct) {
        f32x4 acc = {0.f, 0.f, 0.f, 0.f};
        f32x4 acc2 = {0.f, 0.f, 0.f, 0.f};
#pragma unroll
        for (int ks = 0; ks < 4; ++ks) {
          bf16x8 sH, sL;
          if constexpr (USE_WS) {
            const ushort8* pf = (const ushort8*)SfG;
            sH = __builtin_bit_cast(bf16x8, pf[(ks * 4 + ct) * 64 + lane]);
            sL = __builtin_bit_cast(bf16x8, pf[1024 + (ks * 4 + ct) * 64 + lane]);
          } else {
            sH = __builtin_bit_cast(bf16x8, sSfH[(ks * 4 + ct) * 64 + lane]);
            sL = __builtin_bit_cast(bf16x8, sSfL[(ks * 4 + ct) * 64 + lane]);
          }
          acc = __builtin_amdgcn_mfma_f32_16x16x32_bf16(aH[ks], sH, acc, 0, 0, 0);
          acc2 = __builtin_amdgcn_mfma_f32_16x16x32_bf16(aL[ks], sH, acc2, 0, 0, 0);
          acc2 = __builtin_amdgcn_mfma_f32_16x16x32_bf16(aH[ks], sL, acc2, 0, 0, 0);
        }
#pragma unroll
        for (int reg = 0; reg < 4; ++reg) {
          int orow = r0 + kg * 4 + reg;
          if (orow < SEQ) sBeh[orow][ct * 16 + fr] = acc[reg] + acc2[reg];
        }
      }
    }
  }
  __syncthreads();

  // ---- routing rounds ----
  for (int round = 0; round < NROUNDS; ++round) {
    // Phase A: masked softmax over l; wave w owns capsule k=w.
    {
      const int k = w;
      float v0 = sB[k][lane],       f0 = sMask[lane];
      float v1 = sB[k][lane + 64],  f1 = sMask[lane + 64];
      float v2 = sB[k][lane + 128], f2 = sMask[lane + 128];
      float v3 = 0.f, f3 = 0.f;
      if (lane < SEQ - 192) { v3 = sB[k][lane + 192]; f3 = sMask[lane + 192]; }
      float m = -3.402823466e38f;
      if (f0 > 0.f) m = fmaxf(m, v0);
      if (f1 > 0.f) m = fmaxf(m, v1);
      if (f2 > 0.f) m = fmaxf(m, v2);
      if (f3 > 0.f) m = fmaxf(m, v3);
#pragma unroll
      for (int off = 32; off >= 1; off >>= 1) m = fmaxf(m, __shfl_xor(m, off));
      float e0 = (f0 > 0.f) ? __expf(v0 - m) : 0.f;
      float e1 = (f1 > 0.f) ? __expf(v1 - m) : 0.f;
      float e2 = (f2 > 0.f) ? __expf(v2 - m) : 0.f;
      float e3 = (f3 > 0.f) ? __expf(v3 - m) : 0.f;
      float s = ((e0 + e1) + (e2 + e3));
#pragma unroll
      for (int off = 32; off >= 1; off >>= 1) s += __shfl_xor(s, off);
      float inv = (s > 0.f) ? (1.0f / s) : 0.f;
      sW[k][lane] = e0 * inv;
      sW[k][lane + 64] = e1 * inv;
      sW[k][lane + 128] = e2 * inv;
      if (lane < SEQ - 192) sW[k][lane + 192] = e3 * inv;
    }
    __syncthreads();

    // Phase B + squash: wave w owns k=w.  lane = (lp = lane>>4, dg = lane&15):
    // lane accumulates caps[w][dg*4..+3] over l in {lp, lp+4, ...} (float4),
    // then butterfly-reduce over lp and squash in-wave.
    {
      const int dg = lane & 15;
      const int lp = lane >> 4;
      float ax = 0.f, ay = 0.f, az = 0.f, aw = 0.f;
      for (int l = lp; l < SEQ; l += 4) {
        float wk = sW[w][l];
        float4 b4 = ld4(&sBeh[l][dg * 4]);
        ax = fmaf(wk, b4.x, ax);
        ay = fmaf(wk, b4.y, ay);
        az = fmaf(wk, b4.z, az);
        aw = fmaf(wk, b4.w, aw);
      }
#pragma unroll
      for (int off = 16; off <= 32; off <<= 1) {
        ax += __shfl_xor(ax, off);
        ay += __shfl_xor(ay, off);
        az += __shfl_xor(az, off);
        aw += __shfl_xor(aw, off);
      }
      // squash: q = ||caps||^2 over 64 dims (reduce over dg bits 0..3)
      float q = (ax * ax + ay * ay) + (az * az + aw * aw);
#pragma unroll
      for (int off = 1; off <= 8; off <<= 1) q += __shfl_xor(q, off);
      float n = sqrtf(q);
      float f = (q > 0.f) ? (q / ((1.0f + q) * n)) : 0.f;
      ax *= f; ay *= f; az *= f; aw *= f;
      if (lp == 0) {
        st4(&sCaps[w][dg * 4], make_float4(ax, ay, az, aw));
        if (round == NROUNDS - 1)
          st4(&out[((size_t)b * NCAPS + w) * CDIM + dg * 4], make_float4(ax, ay, az, aw));
      }
    }
    __syncthreads();

    // Phase D: B[k][l] += dot(caps[k], beh[l]).  k = t&7, l strided.
    if (round < NROUNDS - 1) {
      const int k = t & 7;
      float4 cp[16];
#pragma unroll
      for (int i = 0; i < 16; ++i) cp[i] = ld4(&sCaps[k][i * 4]);
      for (int oi = t; oi < NCAPS * SEQ; oi += NT) {
        int l = oi >> 3;
        float px = 0.f, py = 0.f, pz = 0.f, pw = 0.f;
#pragma unroll
        for (int i = 0; i < 16; ++i) {
          float4 b4 = ld4(&sBeh[l][i * 4]);
          px = fmaf(cp[i].x, b4.x, px);
          py = fmaf(cp[i].y, b4.y, py);
          pz = fmaf(cp[i].z, b4.z, pz);
          pw = fmaf(cp[i].w, b4.w, pw);
        }
        sB[k][l] += (px + py) + (pz + pw);
      }
    }
    __syncthreads();
  }
}

extern "C" void kernel_launch(void* const* d_in, const int* in_sizes, int n_in,
                              void* d_out, int out_size, void* d_ws, size_t ws_size,
                              hipStream_t stream) {
  const float* behaviors = (const float*)d_in[0];
  const unsigned char* maskraw = (const unsigned char*)d_in[1];
  const float* S = (const float*)d_in[2];
  const float* B0 = (const float*)d_in[3];
  float* out = (float*)d_out;
  const int B = in_sizes[0] / (SEQ * EMB);
  if (ws_size >= (size_t)(2 * EMB * CDIM * sizeof(unsigned short))) {
    unsigned short* wsS = (unsigned short*)d_ws;
    split_S_kernel<<<dim3((EMB * CDIM + 255) / 256), dim3(256), 0, stream>>>(S, wsS);
    mie_kernel<true><<<dim3(B), dim3(NT), 0, stream>>>(behaviors, maskraw, S, B0, wsS, out);
  } else {
    mie_kernel<false><<<dim3(B), dim3(NT), 0, stream>>>(behaviors, maskraw, S, B0, nullptr, out);
  }
}

// Round 6
// 98.051 us; speedup vs baseline: 1.5160x; 1.5160x over previous
//
#include <hip/hip_runtime.h>
#include <math.h>

#define NCAPS 8
#define SEQ 200
#define EMB 128
#define CDIM 64
#define NROUNDS 3
#define NT 512
#define BPAD 68    // sBeh row pad: 272B rows, 16B-aligned, banks shift by 4/row
#define CPAD 68

typedef __bf16 bf16x8 __attribute__((ext_vector_type(8)));
typedef float f32x4 __attribute__((ext_vector_type(4)));
typedef unsigned short ushort8 __attribute__((ext_vector_type(8)));

__device__ __forceinline__ float4 ld4(const float* p) { return *reinterpret_cast<const float4*>(p); }
__device__ __forceinline__ void st4(float* p, float4 v) { *reinterpret_cast<float4*>(p) = v; }

// RNE float -> bf16 bits
__device__ __forceinline__ unsigned short f2bf(float v) {
  unsigned u = __builtin_bit_cast(unsigned, v);
  u += 0x7FFFu + ((u >> 16) & 1u);
  return (unsigned short)(u >> 16);
}
__device__ __forceinline__ float bf2f(unsigned short b) {
  unsigned u = ((unsigned)b) << 16;
  return __builtin_bit_cast(float, u);
}

// One-time: split S (128x64 fp32) into MFMA-fragment-ordered bf16 hi/lo.
// Element (e,d) -> frag fi = (e>>5)*4 + (d>>4), lane = ((e>>3)&3)*16 + (d&15), j = e&7.
// ws layout: ushort hi[16*64*8] then lo[16*64*8]  (32 KB total)
__global__ void split_S_kernel(const float* __restrict__ S, unsigned short* __restrict__ wsS) {
  int i = blockIdx.x * 256 + threadIdx.x;
  if (i >= EMB * CDIM) return;
  int e = i >> 6, d = i & 63;
  float v = S[i];
  unsigned short h = f2bf(v);
  unsigned short lo = f2bf(v - bf2f(h));
  int fi = (e >> 5) * 4 + (d >> 4);
  int ln = (((e >> 3) & 3) << 4) + (d & 15);
  int j = e & 7;
  wsS[(fi * 64 + ln) * 8 + j] = h;
  wsS[EMB * CDIM + (fi * 64 + ln) * 8 + j] = lo;
}

// NOTE: hipcc treats the 2nd __launch_bounds__ arg as min BLOCKS per CU
// (R5 evidence: (512,4) -> 64-VGPR cap -> 208 MB of spill stores). Use 2:
// 2 blocks x 8 waves = 16 waves/CU -> 128-VGPR cap, no spills at ~110 VGPR.
template <bool USE_WS>
__global__ __launch_bounds__(NT, 2) void mie_kernel(
    const float* __restrict__ behaviors,       // [B][200][128]
    const unsigned char* __restrict__ maskraw, // bool bytes OR int32 OR float32 (detected)
    const float* __restrict__ S,               // [128][64] (only used if !USE_WS)
    const float* __restrict__ B0,              // [8][200]
    const unsigned short* __restrict__ SfG,    // fragment-ordered S hi/lo (if USE_WS)
    float* __restrict__ out)                   // [B][8][64]
{
  __shared__ float sBeh[SEQ][BPAD];     // 54.4 KB (fp32 projection output)
  __shared__ float sB[NCAPS][SEQ];      // 6.4 KB
  __shared__ float sW[NCAPS][SEQ];      // 6.4 KB
  __shared__ float sCaps[NCAPS][CPAD];  // 2.2 KB
  __shared__ float sMask[SEQ];          // 0.8 KB
  __shared__ int sFlagA, sFlagB;
  __shared__ ushort8 sSfH[USE_WS ? 1 : 16 * 64];  // fallback-only S staging
  __shared__ ushort8 sSfL[USE_WS ? 1 : 16 * 64];
  // USE_WS total ~70.3 KB -> 2 blocks/CU (16 waves/CU)

  const int b = blockIdx.x;
  const int t = threadIdx.x;
  const int lane = t & 63;
  const int w = t >> 6;

  // ---- detect mask dtype over first 1KB ----
  if (t == 0) { sFlagA = 0; sFlagB = 0; }
  __syncthreads();
  for (int i = t; i < 1024; i += NT) {
    unsigned char v = maskraw[i];
    if (v != 0) {
      int m = i & 3;
      if (m == 1) atomicOr(&sFlagA, 1);
      else if (m >= 2) atomicOr(&sFlagB, 1);
    }
  }
  __syncthreads();
  const int mode = sFlagA ? 1 : (sFlagB ? 2 : 0);  // 1=bytes, 2=float32, 0=int32

  // ---- load mask, B0 (and fallback S staging) ----
  if (mode == 1) {
    for (int i = t; i < SEQ; i += NT)
      sMask[i] = maskraw[(size_t)b * SEQ + i] ? 1.0f : 0.0f;
  } else if (mode == 2) {
    const float* mf = (const float*)maskraw;
    for (int i = t; i < SEQ; i += NT)
      sMask[i] = (mf[(size_t)b * SEQ + i] != 0.0f) ? 1.0f : 0.0f;
  } else {
    const int* mi = (const int*)maskraw;
    for (int i = t; i < SEQ; i += NT)
      sMask[i] = mi[(size_t)b * SEQ + i] ? 1.0f : 0.0f;
  }
  for (int i = t; i < NCAPS * SEQ; i += NT)
    (&sB[0][0])[i] = B0[i];

  if constexpr (!USE_WS) {
    for (int i = t; i < EMB * CDIM; i += NT) {
      int e = i >> 6, d = i & 63;
      float v = S[i];
      unsigned short h = f2bf(v);
      unsigned short lo = f2bf(v - bf2f(h));
      int fi = (e >> 5) * 4 + (d >> 4);
      int ln = (((e >> 3) & 3) << 4) + (d & 15);
      int j = e & 7;
      ((unsigned short*)&sSfH[fi * 64 + ln])[j] = h;
      ((unsigned short*)&sSfL[fi * 64 + ln])[j] = lo;
    }
  }
  __syncthreads();

  // ---- projection via MFMA: sBeh = behaviors[b] @ S  (split-bf16, 3 terms) ----
  {
    const int fr = lane & 15;   // A row-in-tile; also C col-in-tile
    const int kg = lane >> 4;   // k-group (0..3)
    for (int rt = w; rt < 13; rt += 8) {
      const int r0 = rt * 16;
      const int row = r0 + fr;
      bf16x8 aH[4], aL[4];
#pragma unroll
      for (int ks = 0; ks < 4; ++ks) {
        float a[8];
        if (row < SEQ) {
          const float* p = behaviors + ((size_t)b * SEQ + row) * EMB + ks * 32 + kg * 8;
          float4 u0 = ld4(p), u1 = ld4(p + 4);
          a[0] = u0.x; a[1] = u0.y; a[2] = u0.z; a[3] = u0.w;
          a[4] = u1.x; a[5] = u1.y; a[6] = u1.z; a[7] = u1.w;
        } else {
#pragma unroll
          for (int j = 0; j < 8; ++j) a[j] = 0.f;
        }
        ushort8 h, lo;
#pragma unroll
        for (int j = 0; j < 8; ++j) {
          unsigned short hh = f2bf(a[j]);
          h[j] = hh;
          lo[j] = f2bf(a[j] - bf2f(hh));
        }
        aH[ks] = __builtin_bit_cast(bf16x8, h);
        aL[ks] = __builtin_bit_cast(bf16x8, lo);
      }
#pragma unroll
      for (int ct = 0; ct < 4; ++ct) {
        f32x4 acc = {0.f, 0.f, 0.f, 0.f};
        f32x4 acc2 = {0.f, 0.f, 0.f, 0.f};
#pragma unroll
        for (int ks = 0; ks < 4; ++ks) {
          bf16x8 sH, sL;
          if constexpr (USE_WS) {
            const ushort8* pf = (const ushort8*)SfG;
            sH = __builtin_bit_cast(bf16x8, pf[(ks * 4 + ct) * 64 + lane]);
            sL = __builtin_bit_cast(bf16x8, pf[1024 + (ks * 4 + ct) * 64 + lane]);
          } else {
            sH = __builtin_bit_cast(bf16x8, sSfH[(ks * 4 + ct) * 64 + lane]);
            sL = __builtin_bit_cast(bf16x8, sSfL[(ks * 4 + ct) * 64 + lane]);
          }
          acc = __builtin_amdgcn_mfma_f32_16x16x32_bf16(aH[ks], sH, acc, 0, 0, 0);
          acc2 = __builtin_amdgcn_mfma_f32_16x16x32_bf16(aL[ks], sH, acc2, 0, 0, 0);
          acc2 = __builtin_amdgcn_mfma_f32_16x16x32_bf16(aH[ks], sL, acc2, 0, 0, 0);
        }
#pragma unroll
        for (int reg = 0; reg < 4; ++reg) {
          int orow = r0 + kg * 4 + reg;
          if (orow < SEQ) sBeh[orow][ct * 16 + fr] = acc[reg] + acc2[reg];
        }
      }
    }
  }
  __syncthreads();

  // ---- routing rounds ----
  for (int round = 0; round < NROUNDS; ++round) {
    // Phase A: masked softmax over l; wave w owns capsule k=w.
    {
      const int k = w;
      float v0 = sB[k][lane],       f0 = sMask[lane];
      float v1 = sB[k][lane + 64],  f1 = sMask[lane + 64];
      float v2 = sB[k][lane + 128], f2 = sMask[lane + 128];
      float v3 = 0.f, f3 = 0.f;
      if (lane < SEQ - 192) { v3 = sB[k][lane + 192]; f3 = sMask[lane + 192]; }
      float m = -3.402823466e38f;
      if (f0 > 0.f) m = fmaxf(m, v0);
      if (f1 > 0.f) m = fmaxf(m, v1);
      if (f2 > 0.f) m = fmaxf(m, v2);
      if (f3 > 0.f) m = fmaxf(m, v3);
#pragma unroll
      for (int off = 32; off >= 1; off >>= 1) m = fmaxf(m, __shfl_xor(m, off));
      float e0 = (f0 > 0.f) ? __expf(v0 - m) : 0.f;
      float e1 = (f1 > 0.f) ? __expf(v1 - m) : 0.f;
      float e2 = (f2 > 0.f) ? __expf(v2 - m) : 0.f;
      float e3 = (f3 > 0.f) ? __expf(v3 - m) : 0.f;
      float s = ((e0 + e1) + (e2 + e3));
#pragma unroll
      for (int off = 32; off >= 1; off >>= 1) s += __shfl_xor(s, off);
      float inv = (s > 0.f) ? (1.0f / s) : 0.f;
      sW[k][lane] = e0 * inv;
      sW[k][lane + 64] = e1 * inv;
      sW[k][lane + 128] = e2 * inv;
      if (lane < SEQ - 192) sW[k][lane + 192] = e3 * inv;
    }
    __syncthreads();

    // Phase B + squash: wave w owns k=w.  lane = (lp = lane>>4, dg = lane&15):
    // lane accumulates caps[w][dg*4..+3] over l in {lp, lp+4, ...} (float4),
    // then butterfly-reduce over lp and squash in-wave.
    {
      const int dg = lane & 15;
      const int lp = lane >> 4;
      float ax = 0.f, ay = 0.f, az = 0.f, aw = 0.f;
      for (int l = lp; l < SEQ; l += 4) {
        float wk = sW[w][l];
        float4 b4 = ld4(&sBeh[l][dg * 4]);
        ax = fmaf(wk, b4.x, ax);
        ay = fmaf(wk, b4.y, ay);
        az = fmaf(wk, b4.z, az);
        aw = fmaf(wk, b4.w, aw);
      }
#pragma unroll
      for (int off = 16; off <= 32; off <<= 1) {
        ax += __shfl_xor(ax, off);
        ay += __shfl_xor(ay, off);
        az += __shfl_xor(az, off);
        aw += __shfl_xor(aw, off);
      }
      // squash: q = ||caps||^2 over 64 dims (reduce over dg bits 0..3)
      float q = (ax * ax + ay * ay) + (az * az + aw * aw);
#pragma unroll
      for (int off = 1; off <= 8; off <<= 1) q += __shfl_xor(q, off);
      float n = sqrtf(q);
      float f = (q > 0.f) ? (q / ((1.0f + q) * n)) : 0.f;
      ax *= f; ay *= f; az *= f; aw *= f;
      if (lp == 0) {
        st4(&sCaps[w][dg * 4], make_float4(ax, ay, az, aw));
        if (round == NROUNDS - 1)
          st4(&out[((size_t)b * NCAPS + w) * CDIM + dg * 4], make_float4(ax, ay, az, aw));
      }
    }
    __syncthreads();

    // Phase D: B[k][l] += dot(caps[k], beh[l]).  k = t&7, l strided.
    if (round < NROUNDS - 1) {
      const int k = t & 7;
      float4 cp[16];
#pragma unroll
      for (int i = 0; i < 16; ++i) cp[i] = ld4(&sCaps[k][i * 4]);
      for (int oi = t; oi < NCAPS * SEQ; oi += NT) {
        int l = oi >> 3;
        float px = 0.f, py = 0.f, pz = 0.f, pw = 0.f;
#pragma unroll
        for (int i = 0; i < 16; ++i) {
          float4 b4 = ld4(&sBeh[l][i * 4]);
          px = fmaf(cp[i].x, b4.x, px);
          py = fmaf(cp[i].y, b4.y, py);
          pz = fmaf(cp[i].z, b4.z, pz);
          pw = fmaf(cp[i].w, b4.w, pw);
        }
        sB[k][l] += (px + py) + (pz + pw);
      }
    }
    __syncthreads();
  }
}

extern "C" void kernel_launch(void* const* d_in, const int* in_sizes, int n_in,
                              void* d_out, int out_size, void* d_ws, size_t ws_size,
                              hipStream_t stream) {
  const float* behaviors = (const float*)d_in[0];
  const unsigned char* maskraw = (const unsigned char*)d_in[1];
  const float* S = (const float*)d_in[2];
  const float* B0 = (const float*)d_in[3];
  float* out = (float*)d_out;
  const int B = in_sizes[0] / (SEQ * EMB);
  if (ws_size >= (size_t)(2 * EMB * CDIM * sizeof(unsigned short))) {
    unsigned short* wsS = (unsigned short*)d_ws;
    split_S_kernel<<<dim3((EMB * CDIM + 255) / 256), dim3(256), 0, stream>>>(S, wsS);
    mie_kernel<true><<<dim3(B), dim3(NT), 0, stream>>>(behaviors, maskraw, S, B0, wsS, out);
  } else {
    mie_kernel<false><<<dim3(B), dim3(NT), 0, stream>>>(behaviors, maskraw, S, B0, nullptr, out);
  }
}